// Round 12
// baseline (391.418 us; speedup 1.0000x reference)
//
#include <hip/hip_runtime.h>
#include <hip/hip_bf16.h>
#include <math.h>

typedef __bf16 bf16_t;
typedef __bf16 bf16x8 __attribute__((ext_vector_type(8)));
typedef float floatx4 __attribute__((ext_vector_type(4)));
typedef int intx4 __attribute__((ext_vector_type(4)));

#define T_TOK 2048
#define HID 2048
#define NH 16
#define D_NOPE 128
#define D_ROPE 64
#define D_QK 192
#define D_V 128
#define Q_LORA 1536
#define KV_LORA 512
#define QKV_N 2112            // 1536+512+64
#define QKV_NPAD 2176         // padded to 17*128
#define SCALING 0.07216878364870323f
#define LOG2E 1.442695041f
#define EXP_C1 (SCALING * LOG2E)      // score -> exp2 arg scale
#define EXP_C2 (12.0f * LOG2E)        // fixed bias (replaces online max; safe to s~100)

#define MFMA_BF16(a, b, c) __builtin_amdgcn_mfma_f32_16x16x32_bf16(a, b, c, 0, 0, 0)

// async 16B global->LDS (verified m97 pattern; LDS dest must be lane-linear)
__device__ __forceinline__ void gload16(const void* g, void* l) {
    __builtin_amdgcn_global_load_lds(
        (const __attribute__((address_space(1))) unsigned int*)g,
        (__attribute__((address_space(3))) unsigned int*)l, 16, 0, 0);
}

// ---------------------------------------------------------------------------
// MFMA GEMM body (round-8 verified: 256 threads, 128x128 tile, BK=64,
// 2-phase dbuf + chunk-XOR swizzle). Ast/Bst = row strides (may differ from K
// so A can be a column-slice of a wider matrix).
// MODE 0: fp32 C (gemm_o).
// MODE 1: bf16 C scaled by rq[row] from sqq   (q_b GEMM; rmsnorm fused).
// MODE 2: kv epilogue scaled by rkv[row]: k-nope -> kfull (192-stride),
//         v -> transposed write to vT[h][d][t] via LDS.
// MODE 3: bf16 C + per-row sumsq atomics (qkv_a GEMM; feeds rmsnorm).
// ---------------------------------------------------------------------------
template <int MODE>
__device__ __forceinline__ void gemm_body(
    const bf16_t* __restrict__ A, const bf16_t* __restrict__ Bt,
    float* __restrict__ Cf, bf16_t* __restrict__ Cb,
    bf16_t* __restrict__ kfull, bf16_t* __restrict__ vT,
    float* __restrict__ sqq, float* __restrict__ sqkv,
    int N, int K, int Ast, int Bst, int m0, int n0, bf16_t* S)
{
    bf16_t* As = S;               // 2 x 8192
    bf16_t* Bs = S + 16384;       // 2 x 8192
    const int tid = threadIdx.x;
    const int lane = tid & 63;
    const int w = tid >> 6;
    const int wm = w >> 1, wn = w & 1;
    const int l15 = lane & 15, quad = lane >> 4;
    const int ckey = (l15 >> 1) & 3;           // read-side chunk XOR key

    floatx4 acc[4][4] = {};

// stage tile (k0_) into buffer db_; source chunk pre-swizzled so that
// LDS[kk2][r][c] holds global chunk c ^ ((r>>1)&3)  (involution)
#define GSTAGE(db_, k0_)                                                                 \
    do {                                                                                 \
        _Pragma("unroll")                                                                \
        for (int it = 0; it < 4; ++it) {                                                 \
            int slot = it * 256 + tid;                                                   \
            int kk2 = slot >> 9;                                                         \
            int r = (slot >> 2) & 127;                                                   \
            int c = slot & 3;                                                            \
            int cs = c ^ ((r >> 1) & 3);                                                 \
            gload16((const char*)(A + (size_t)(m0 + r) * Ast + (k0_) + kk2 * 32 + cs * 8),\
                    (char*)(As + (size_t)(db_)*8192) + slot * 16);                       \
            gload16((const char*)(Bt + (size_t)(n0 + r) * Bst + (k0_) + kk2 * 32 + cs * 8),\
                    (char*)(Bs + (size_t)(db_)*8192) + slot * 16);                       \
        }                                                                                \
    } while (0)

    GSTAGE(0, 0);
    int db = 0;
    for (int k0 = 0; k0 < K; k0 += 64) {
        __syncthreads();                       // drains prefetch (issued 1 phase ago)
        if (k0 + 64 < K) GSTAGE(db ^ 1, k0 + 64);
        const bf16_t* Ab = As + (size_t)db * 8192;
        const bf16_t* Bb = Bs + (size_t)db * 8192;
#pragma unroll
        for (int kk2 = 0; kk2 < 2; ++kk2) {
            bf16x8 af[4], bfr[4];
#pragma unroll
            for (int mi = 0; mi < 4; ++mi)
                af[mi] = *(const bf16x8*)(Ab + kk2 * 4096 +
                                          (wm * 64 + mi * 16 + l15) * 32 +
                                          (quad ^ ckey) * 8);
#pragma unroll
            for (int ni = 0; ni < 4; ++ni)
                bfr[ni] = *(const bf16x8*)(Bb + kk2 * 4096 +
                                           (wn * 64 + ni * 16 + l15) * 32 +
                                           (quad ^ ckey) * 8);
#pragma unroll
            for (int mi = 0; mi < 4; ++mi)
#pragma unroll
                for (int ni = 0; ni < 4; ++ni)
                    acc[mi][ni] = MFMA_BF16(af[mi], bfr[ni], acc[mi][ni]);
        }
        db ^= 1;
    }
#undef GSTAGE

    if (MODE == 3) {
        // bf16 C + per-row sumsq (bucket by n0: q cols <1536, kv [1536,2048))
#pragma unroll
        for (int mi = 0; mi < 4; ++mi)
#pragma unroll
            for (int ni = 0; ni < 4; ++ni)
#pragma unroll
                for (int r = 0; r < 4; ++r) {
                    int row = m0 + wm * 64 + mi * 16 + quad * 4 + r;
                    int col = n0 + wn * 64 + ni * 16 + l15;
                    Cb[(size_t)row * N + col] = (bf16_t)acc[mi][ni][r];
                }
        float* sq = (n0 + 128 <= Q_LORA) ? sqq
                  : ((n0 >= Q_LORA && n0 + 128 <= Q_LORA + KV_LORA) ? sqkv : nullptr);
        if (sq) {
#pragma unroll
            for (int mi = 0; mi < 4; ++mi)
#pragma unroll
                for (int r = 0; r < 4; ++r) {
                    float s = 0.f;
#pragma unroll
                    for (int ni = 0; ni < 4; ++ni) {
                        float v = acc[mi][ni][r]; s += v * v;
                    }
                    s += __shfl_xor(s, 1); s += __shfl_xor(s, 2);
                    s += __shfl_xor(s, 4); s += __shfl_xor(s, 8);
                    if (l15 == 0)
                        atomicAdd(&sq[m0 + wm * 64 + mi * 16 + quad * 4 + r], s);
                }
        }
        return;
    }

    if (MODE == 1) {
        // q = (qkv_a @ g.w_q_b) * rq[row]   (rmsnorm scale commuted to output)
#pragma unroll
        for (int mi = 0; mi < 4; ++mi)
#pragma unroll
            for (int r = 0; r < 4; ++r) {
                int row = m0 + wm * 64 + mi * 16 + quad * 4 + r;
                float rq = rsqrtf(sqq[row] * (1.f / Q_LORA) + 1e-6f);
#pragma unroll
                for (int ni = 0; ni < 4; ++ni) {
                    int col = n0 + wn * 64 + ni * 16 + l15;
                    Cb[(size_t)row * N + col] = (bf16_t)(acc[mi][ni][r] * rq);
                }
            }
        return;
    }

    if (MODE == 2) {
        const int hh = n0 >> 8;
        if ((n0 & 255) == 0) {
            // ---- k-nope block ----
#pragma unroll
            for (int mi = 0; mi < 4; ++mi)
#pragma unroll
                for (int r = 0; r < 4; ++r) {
                    int row = m0 + wm * 64 + mi * 16 + quad * 4 + r;
                    float rkv = rsqrtf(sqkv[row] * (1.f / KV_LORA) + 1e-6f);
#pragma unroll
                    for (int ni = 0; ni < 4; ++ni) {
                        int dd = wn * 64 + ni * 16 + l15;
                        kfull[((size_t)hh * T_TOK + row) * 192 + dd] =
                            (bf16_t)(acc[mi][ni][r] * rkv);
                    }
                }
        } else {
            // ---- v block: scale + transpose via LDS, write vT[h][d][t] ----
            __syncthreads();                   // all waves done reading As/Bs
            bf16_t* Tq = S;                    // [128 d][stride 136] bf16
#pragma unroll
            for (int mi = 0; mi < 4; ++mi)
#pragma unroll
                for (int r = 0; r < 4; ++r) {
                    int rloc = wm * 64 + mi * 16 + quad * 4 + r;    // t - m0
                    float rkv = rsqrtf(sqkv[m0 + rloc] * (1.f / KV_LORA) + 1e-6f);
#pragma unroll
                    for (int ni = 0; ni < 4; ++ni) {
                        int cloc = wn * 64 + ni * 16 + l15;         // d
                        Tq[cloc * 136 + rloc] = (bf16_t)(acc[mi][ni][r] * rkv);
                    }
                }
            __syncthreads();
#pragma unroll
            for (int pass = 0; pass < 8; ++pass) {
                int dcol = pass * 16 + w * 4 + quad;
                bf16x8 vv = *(const bf16x8*)(Tq + dcol * 136 + l15 * 8);
                *(bf16x8*)(vT + ((size_t)hh * 128 + dcol) * T_TOK + m0 + l15 * 8) = vv;
            }
        }
        return;
    }

    // MODE 0: fp32 C
#pragma unroll
    for (int mi = 0; mi < 4; ++mi)
#pragma unroll
        for (int ni = 0; ni < 4; ++ni)
#pragma unroll
            for (int r = 0; r < 4; ++r) {
                int row = m0 + wm * 64 + mi * 16 + quad * 4 + r;
                int col = n0 + wn * 64 + ni * 16 + l15;
                Cf[(size_t)row * N + col] = acc[mi][ni][r];
            }
}

// qkv_a GEMM: bf16 out + sumsq atomics (rmsnorm stats fused into epilogue)
__global__ __launch_bounds__(256) void gemm_qkv_a(
    const bf16_t* __restrict__ hbf, const bf16_t* __restrict__ wt,
    bf16_t* __restrict__ qkv_ab, float* __restrict__ sqq, float* __restrict__ sqkv)
{
    __shared__ __align__(16) bf16_t S[4 * 8192];    // 64 KB
    gemm_body<3>(hbf, wt, nullptr, qkv_ab, nullptr, nullptr, sqq, sqkv,
                 QKV_NPAD, HID, HID, HID, blockIdx.y * 128, blockIdx.x * 128, S);
}

// Merged q_b + kv_b GEMMs, both reading raw bf16 qkv_a (stride 2176) with
// the rmsnorm row-scale applied in the epilogue (qn/kvn eliminated).
__global__ __launch_bounds__(256) void gemm_dual(
    const bf16_t* __restrict__ qkv_ab, const bf16_t* __restrict__ wqb,
    bf16_t* __restrict__ qbuf, const bf16_t* __restrict__ wkvb,
    bf16_t* __restrict__ kfull, bf16_t* __restrict__ vT,
    float* __restrict__ sqq, float* __restrict__ sqkv)
{
    __shared__ __align__(16) bf16_t S[4 * 8192];    // 64 KB
    int id = blockIdx.x;
    if (id < 384) {
        gemm_body<1>(qkv_ab, wqb, nullptr, qbuf, nullptr, nullptr, sqq, nullptr,
                     3072, Q_LORA, QKV_NPAD, Q_LORA,
                     (id / 24) * 128, (id % 24) * 128, S);
    } else {
        int i2 = id - 384;
        gemm_body<2>(qkv_ab + Q_LORA, wkvb, nullptr, nullptr, kfull, vT,
                     nullptr, sqkv,
                     4096, KV_LORA, QKV_NPAD, KV_LORA,
                     (i2 / 32) * 128, (i2 % 32) * 128, S);
    }
}

__global__ __launch_bounds__(256) void gemm_out(
    const bf16_t* __restrict__ attn_o, const bf16_t* __restrict__ wto,
    float* __restrict__ out)
{
    __shared__ __align__(16) bf16_t S[4 * 8192];    // 64 KB
    gemm_body<0>(attn_o, wto, out, nullptr, nullptr, nullptr, nullptr, nullptr,
                 HID, HID, HID, HID, blockIdx.y * 128, blockIdx.x * 128, S);
}

// ---------------------------------------------------------------------------
// Weight prep: 4 weight transposes (g_q/g_kv folded into w_q_b/w_kv_b) +
// hidden fp32->bf16 cvt + sumsq-buffer zeroing, one launch.
// ---------------------------------------------------------------------------
__global__ void transpose_all(const float* __restrict__ w0, const float* __restrict__ w1,
                              const float* __restrict__ w2, const float* __restrict__ w3,
                              const float* __restrict__ hidden,
                              const float* __restrict__ g_q, const float* __restrict__ g_kv,
                              bf16_t* __restrict__ o0, bf16_t* __restrict__ o1,
                              bf16_t* __restrict__ o2, bf16_t* __restrict__ o3,
                              bf16_t* __restrict__ hbf, float* __restrict__ sqbuf) {
    int n0 = blockIdx.x * 32, k0 = blockIdx.y * 32;
    int tx = threadIdx.x, ty = threadIdx.y;
    if (blockIdx.z == 4) {      // cvt hidden -> hbf + zero sq buffers
        if (blockIdx.x == 0 && blockIdx.y == 0) {
            int t = ty * 32 + tx;
            for (int j = t; j < 4096; j += 256) sqbuf[j] = 0.f;
        }
        if (n0 >= 2048 || k0 >= 2048) return;
        for (int i = ty; i < 32; i += 8)
            hbf[(size_t)(k0 + i) * 2048 + n0 + tx] =
                (bf16_t)hidden[(size_t)(k0 + i) * 2048 + n0 + tx];
        return;
    }
    const float* in; bf16_t* out; const float* g; int K, N;
    switch (blockIdx.z) {
        case 0: in = w0; out = o0; g = nullptr; K = 2048; N = 2112; break;
        case 1: in = w1; out = o1; g = g_q;     K = 1536; N = 3072; break;
        case 2: in = w2; out = o2; g = g_kv;    K = 512;  N = 4096; break;
        default: in = w3; out = o3; g = nullptr; K = 2048; N = 2048; break;
    }
    if (n0 >= N || k0 >= K) return;
    __shared__ float tile[32][33];
    for (int i = ty; i < 32; i += 8)
        tile[i][tx] = in[(size_t)(k0 + i) * N + n0 + tx];
    __syncthreads();
    float gk = g ? g[k0 + tx] : 1.f;
    for (int i = ty; i < 32; i += 8)
        out[(size_t)(n0 + i) * K + k0 + tx] = (bf16_t)(tile[tx][i] * gk);
}

// ---------------------------------------------------------------------------
// mid_fuse_lite: Q-rope cos/sin table + rope(k_pe) broadcast into
// kfull[h][t][128..192). (rmsnorm stats + qn/kvn now fused into the GEMMs.)
// ---------------------------------------------------------------------------
__global__ void mid_fuse_lite(const bf16_t* __restrict__ qkv_ab,
                              const int* __restrict__ pos,
                              float2* __restrict__ ropet, bf16_t* __restrict__ kfull) {
    int t = blockIdx.x, tid = threadIdx.x;
    if (tid >= 32) return;
    int i = tid;
    double inv = pow(10000.0, -(double)(2 * i) / 64.0);
    double fd = (double)pos[t] * inv;
    float c = (float)cos(fd), s = (float)sin(fd);
    ropet[t * 32 + i] = make_float2(c, s);
    float x1 = (float)qkv_ab[(size_t)t * QKV_NPAD + Q_LORA + KV_LORA + 2 * i];
    float x2 = (float)qkv_ab[(size_t)t * QKV_NPAD + Q_LORA + KV_LORA + 2 * i + 1];
    bf16_t v0 = (bf16_t)(x1 * c - x2 * s);
    bf16_t v1 = (bf16_t)(x1 * s + x2 * c);
#pragma unroll
    for (int h = 0; h < NH; ++h) {
        kfull[((size_t)h * T_TOK + t) * 192 + 128 + 2 * i] = v0;
        kfull[((size_t)h * T_TOK + t) * 192 + 128 + 2 * i + 1] = v1;
    }
}

// ---------------------------------------------------------------------------
// Flash attention v9 — LDS diet 80->48 KB => 3 blocks/CU (+50% occupancy):
//  * K single-buffered (24 KB) with a 3-barrier schedule that keeps the full
//    prefetch window: (A) bar -> QK -> (B) bar -> issue STAGE_KN(next)+
//    VLOAD(next) -> softmax+PV (~2000cy for loads to land) -> (C) bar (drains
//    prefetch vmcnt) -> VWRITE. K is only read in QK so (B) frees the buffer.
//  * p_s halved to [128][32] (8 KB): softmax+PV split per ks-half (P-cols
//    ks*32..+31); rows wave-private + per-wave in-order DS => no barrier for
//    the half-buffer reuse. Chunk-XOR key (row>>1)&3 keeps reads <=2-way.
//  * everything else (QK/PV MFMA, T14 V staging, in-reg Q-rope, epilogue)
//    identical to the round-8/11 verified version.
// ---------------------------------------------------------------------------
__global__ __launch_bounds__(256, 3) void attn_part(
    const bf16_t* __restrict__ qbuf, const bf16_t* __restrict__ kfull,
    const bf16_t* __restrict__ vT, const float2* __restrict__ ropet,
    bf16_t* __restrict__ oP0, bf16_t* __restrict__ oP1, float* __restrict__ l_part)
{
    const int id = blockIdx.x;
    const int h = id & 15;
    const int c = (id >> 4) & 3;
    const int qt = 15 - (id >> 6);
    const int q0 = qt * 128;
    const int nTile = 2 * (qt + 1);
    const int tbase = nTile >> 2, trem = nTile & 3;    // trem in {0,2}
    const int sz = tbase + (c < trem ? 1 : 0);
    const int sBeg = c * tbase + (c < trem ? c : trem);
    const int sEnd = sBeg + sz;
    const int unit = qt * 16 + h;
    const int tid = threadIdx.x, lane = tid & 63, w = tid >> 6;
    const int l15 = lane & 15, quad = lane >> 4;
    const int ckey = (l15 >> 1) & 3;                   // read-side chunk XOR key

    __shared__ __align__(16) bf16_t kn[6 * 64 * 32];       // 24 KB single (K incl. pe)
    __shared__ __align__(16) bf16_t vt2[2 * 128 * 32];     // 16 KB
    __shared__ __align__(16) bf16_t p_s[128 * 32];         // 8 KB half-P, swizzled

    // Q fragments: 2 strips x 6 k-steps (rows q0 + w*32 + st*16 + l15)
    bf16x8 qf[2][6];
#pragma unroll
    for (int st = 0; st < 2; ++st) {
        const bf16_t* qp = qbuf + (size_t)(q0 + w * 32 + st * 16 + l15) * (NH * D_QK) +
                           h * D_QK;
#pragma unroll
        for (int kk = 0; kk < 6; ++kk)
            qf[st][kk] = *(const bf16x8*)(qp + kk * 32 + quad * 8);
    }
    // in-register rope on q_pe (cols 128..191 -> kk 4,5)
#pragma unroll
    for (int st = 0; st < 2; ++st) {
        int t = q0 + w * 32 + st * 16 + l15;
#pragma unroll
        for (int kk = 4; kk < 6; ++kk)
#pragma unroll
            for (int p = 0; p < 4; ++p) {
                float2 cs = ropet[t * 32 + (kk - 4) * 16 + quad * 4 + p];
                float x1 = (float)qf[st][kk][2 * p], x2 = (float)qf[st][kk][2 * p + 1];
                qf[st][kk][2 * p] = (bf16_t)(x1 * cs.x - x2 * cs.y);
                qf[st][kk][2 * p + 1] = (bf16_t)(x1 * cs.y + x2 * cs.x);
            }
    }

    bf16x8 ones;
#pragma unroll
    for (int j = 0; j < 8; ++j) ones[j] = (bf16_t)1.0f;

    floatx4 o[2][8] = {};
    floatx4 lac[2] = {};
    intx4 vreg[4];

// K staging: gload_lds dest is lane-linear, so pre-swizzle the GLOBAL source
// chunk (cc ^ (s>>1)&3); reads undo it with quad ^ ckey (involution).
#define STAGE_KN(s0_)                                                                    \
    do {                                                                                 \
        _Pragma("unroll")                                                                \
        for (int it = 0; it < 6; ++it) {                                                 \
            int slot = it * 256 + tid;                                                   \
            int kk = slot >> 8, s = (slot >> 2) & 63, cc = slot & 3;                     \
            int cs = cc ^ ((s >> 1) & 3);                                                \
            gload16((const char*)(kfull + ((size_t)h * T_TOK + (s0_) + s) * 192 +        \
                                  kk * 32 + cs * 8),                                     \
                    (char*)kn + slot * 16);                                              \
        }                                                                                \
    } while (0)

// V staging split (T14): issue loads early (latency hides under compute),
// ds_write late at the SWIZZLED LDS position.
#define VLOAD(s0_)                                                                       \
    do {                                                                                 \
        _Pragma("unroll")                                                                \
        for (int it = 0; it < 4; ++it) {                                                 \
            int slot = it * 256 + tid;                                                   \
            int ks = slot >> 9, d = (slot >> 2) & 127, cc = slot & 3;                    \
            vreg[it] = *(const intx4*)(vT + ((size_t)h * 128 + d) * T_TOK + (s0_) +      \
                                       ks * 32 + cc * 8);                                \
        }                                                                                \
    } while (0)

#define VWRITE()                                                                         \
    do {                                                                                 \
        _Pragma("unroll")                                                                \
        for (int it = 0; it < 4; ++it) {                                                 \
            int slot = it * 256 + tid;                                                   \
            int ks = slot >> 9, d = (slot >> 2) & 127, cc = slot & 3;                    \
            *(intx4*)((char*)vt2 +                                                       \
                      (size_t)((ks * 512 + d * 4 + (cc ^ ((d >> 1) & 3))) * 16)) =       \
                vreg[it];                                                                \
        }                                                                                \
    } while (0)

    if (sz > 0) {
        STAGE_KN(sBeg * 64);
        VLOAD(sBeg * 64);
        VWRITE();
    }

    for (int si = sBeg; si < sEnd; ++si) {
        const int s0 = si * 64;
        __syncthreads();                        // (A) kn + vt ready (prev writes done)

        // ---- S = Q K^T (B-frags shared across strips) ----
        floatx4 s_acc[2][4] = {};
        __builtin_amdgcn_s_setprio(1);
#pragma unroll
        for (int ni = 0; ni < 4; ++ni) {
#pragma unroll
            for (int kk = 0; kk < 6; ++kk) {
                bf16x8 b = *(const bf16x8*)(kn + kk * 2048 +
                                            (ni * 16 + l15) * 32 + (quad ^ ckey) * 8);
                s_acc[0][ni] = MFMA_BF16(qf[0][kk], b, s_acc[0][ni]);
                s_acc[1][ni] = MFMA_BF16(qf[1][kk], b, s_acc[1][ni]);
            }
        }
        __builtin_amdgcn_s_setprio(0);

        __syncthreads();                        // (B) all waves done reading kn
        if (si + 1 < sEnd) {
            STAGE_KN(s0 + 64);                  // async into kn; lands under softmax+PV
            VLOAD(s0 + 64);                     // V regs: same window
        }

        // ---- per ks-half: softmax (ni=2ks,2ks+1) -> p_s, then PV(ks) ----
        const bool diag = (si >= 2 * qt);
#pragma unroll
        for (int ks = 0; ks < 2; ++ks) {
#pragma unroll
            for (int st = 0; st < 2; ++st)
#pragma unroll
                for (int nl = 0; nl < 2; ++nl)
#pragma unroll
                    for (int r = 0; r < 4; ++r) {
                        int prow = w * 32 + st * 16 + quad * 4 + r;
                        int cloc = nl * 16 + l15;
                        float pv = exp2f(s_acc[st][ks * 2 + nl][r] * EXP_C1 - EXP_C2);
                        if (diag && (s0 + ks * 32 + cloc) > (q0 + prow)) pv = 0.f;
                        p_s[prow * 32 + ((((cloc >> 3) ^ ((prow >> 1) & 3))) << 3) +
                            (cloc & 7)] = (bf16_t)pv;
                    }
            __builtin_amdgcn_s_setprio(1);
            bf16x8 a0, a1;
            {
                int arow = w * 32 + l15;
                a0 = *(const bf16x8*)(p_s + arow * 32 +
                                      ((quad ^ ((arow >> 1) & 3)) << 3));
                arow += 16;
                a1 = *(const bf16x8*)(p_s + arow * 32 +
                                      ((quad ^ ((arow >> 1) & 3)) << 3));
            }
            lac[0] = MFMA_BF16(a0, ones, lac[0]);
            lac[1] = MFMA_BF16(a1, ones, lac[1]);
#pragma unroll
            for (int ni = 0; ni < 8; ++ni) {
                bf16x8 b = *(const bf16x8*)(vt2 + ks * 4096 +
                                            (ni * 16 + l15) * 32 + (quad ^ ckey) * 8);
                o[0][ni] = MFMA_BF16(a0, b, o[0][ni]);
                o[1][ni] = MFMA_BF16(a1, b, o[1][ni]);
            }
            __builtin_amdgcn_s_setprio(0);
        }

        __syncthreads();                        // (C) vt free + prefetch vmcnt drained
        if (si + 1 < sEnd) VWRITE();            // write next V (regs landed)
    }

    // ---- write partials: o (bf16, unnormalized) + l (fp32) ----
    bf16_t* op = ((c < 2) ? oP0 : oP1) + (size_t)(unit * 2 + (c & 1)) * 128 * 128;
#pragma unroll
    for (int st = 0; st < 2; ++st) {
#pragma unroll
        for (int ni = 0; ni < 8; ++ni)
#pragma unroll
            for (int r = 0; r < 4; ++r) {
                int lrow = w * 32 + st * 16 + quad * 4 + r;
                op[(size_t)lrow * 128 + ni * 16 + l15] = (bf16_t)o[st][ni][r];
            }
        if (l15 == 0)
#pragma unroll
            for (int r = 0; r < 4; ++r) {
                int lrow = w * 32 + st * 16 + quad * 4 + r;
                l_part[((size_t)unit * 4 + c) * 128 + lrow] = lac[st][r];
            }
    }
#undef STAGE_KN
#undef VLOAD
#undef VWRITE
}

// ---------------------------------------------------------------------------
// Combine: attn_o = (o0+o1+o2+o3) / (l0+l1+l2+l3)
// ---------------------------------------------------------------------------
__global__ void attn_combine(const bf16_t* __restrict__ oP0,
                             const bf16_t* __restrict__ oP1,
                             const float* __restrict__ l_part,
                             bf16_t* __restrict__ attn_o)
{
    int idx = blockIdx.x * 256 + threadIdx.x;   // t*256 + col-group (8 cols each)
    int t = idx >> 8, cg = idx & 255;
    int col = cg * 8;
    int h = col >> 7, d = col & 127;
    int qt = t >> 7, lrow = t & 127;
    size_t unit = (size_t)qt * 16 + h;
    const float* lp = l_part + unit * 4 * 128 + lrow;
    float inv = 1.f / (lp[0] + lp[128] + lp[256] + lp[384]);
    size_t r0 = ((unit * 2 + 0) * 128 + lrow) * 128 + d;
    size_t r1 = ((unit * 2 + 1) * 128 + lrow) * 128 + d;
    bf16x8 a0 = *(const bf16x8*)(oP0 + r0);
    bf16x8 a1 = *(const bf16x8*)(oP0 + r1);
    bf16x8 a2 = *(const bf16x8*)(oP1 + r0);
    bf16x8 a3 = *(const bf16x8*)(oP1 + r1);
    bf16x8 out;
#pragma unroll
    for (int j = 0; j < 8; ++j)
        out[j] = (bf16_t)(((float)a0[j] + (float)a1[j] + (float)a2[j] + (float)a3[j]) * inv);
    *(bf16x8*)(attn_o + (size_t)t * (NH * D_V) + col) = out;
}

// ---------------------------------------------------------------------------
extern "C" void kernel_launch(void* const* d_in, const int* in_sizes, int n_in,
                              void* d_out, int out_size, void* d_ws, size_t ws_size,
                              hipStream_t stream) {
    const float* hidden = (const float*)d_in[0];
    const int* positions = (const int*)d_in[1];
    const float* w_qkv_a = (const float*)d_in[2];
    const float* g_q = (const float*)d_in[3];
    const float* w_q_b = (const float*)d_in[4];
    const float* g_kv = (const float*)d_in[5];
    const float* w_kv_b = (const float*)d_in[6];
    const float* w_o = (const float*)d_in[7];
    float* out = (float*)d_out;

    // ---- workspace layout (~94.5 MB, round-8 region map) ----
    char* p = (char*)d_ws;
    bf16_t* qkv_ab = (bf16_t*)p;                    // [2048][2176] bf16 (8.9 MB)
    bf16_t* attn_o = (bf16_t*)p;                    // alias (qkv_ab dead by then)
    p += (size_t)T_TOK * QKV_NPAD * 4;              // region still fp32-sized
    bf16_t* hbf = (bf16_t*)p;                       // [2048][2048] bf16
    p += (size_t)T_TOK * HID * 2;
    bf16_t* qbuf = (bf16_t*)p;  p += (size_t)T_TOK * NH * D_QK * 2;   // [2048][3072]
    bf16_t* vtmp = (bf16_t*)p;  p += (size_t)T_TOK * NH * D_V * 2;    // scratch region
    bf16_t* kfull = (bf16_t*)p; p += (size_t)NH * T_TOK * 192 * 2;    // [16][2048][192]
    bf16_t* vT = (bf16_t*)p;    p += (size_t)NH * 128 * T_TOK * 2;    // [16][128][2048]
    bf16_t* wt_qkv_a = (bf16_t*)p; p += (size_t)QKV_NPAD * HID * 2;   // [2176][2048]
    bf16_t* wt_q_b = (bf16_t*)p;   p += (size_t)3072 * Q_LORA * 2;    // [3072][1536]
    bf16_t* wt_kv_b = (bf16_t*)p;  p += (size_t)4096 * KV_LORA * 2;   // [4096][512]
    bf16_t* wt_o = (bf16_t*)p;                                        // [2048][2048]

    // overlays of dead-by-then regions:
    //   ropet  f32x2 [2048][32] = 512 KB at vtmp+0      (written mid_fuse_lite)
    //   l_part f32 [256][4][128] = 512 KB at vtmp+1MB
    //   sq_q/sq_kv f32 2048+2048 = 16 KB at vtmp+2MB    (zeroed transpose_all)
    //   oP0 bf16 [256][2][128][128] = 16.78 MB over wt_qkv_a + wt_q_b
    //   oP1 bf16 [256][2][128][128] = 16.78 MB over qkv_ab tail + hbf
    float2* ropet = (float2*)vtmp;
    float* l_part = (float*)((char*)vtmp + (1 << 20));
    float* sq_q = (float*)((char*)vtmp + (2 << 20));
    float* sq_kv = sq_q + 2048;
    bf16_t* oP0 = wt_qkv_a;
    bf16_t* oP1 = (bf16_t*)((char*)d_ws + (size_t)T_TOK * HID * 2);

    dim3 tb(32, 8);

    // 0. weight transposes (g folded into w_q_b/w_kv_b) + hidden cvt + sq zero
    transpose_all<<<dim3(128, 64, 5), tb, 0, stream>>>(
        w_qkv_a, w_q_b, w_kv_b, w_o, hidden, g_q, g_kv,
        wt_qkv_a, wt_q_b, wt_kv_b, wt_o, hbf, sq_q);

    // 1. qkv_a (bf16) = hidden @ w_qkv_a, + per-row sumsq atomics
    gemm_qkv_a<<<dim3(QKV_NPAD / 128, T_TOK / 128), 256, 0, stream>>>(
        hbf, wt_qkv_a, qkv_ab, sq_q, sq_kv);

    // 2. rope table + rope(k_pe)->kfull (rmsnorm now lives in the GEMMs)
    mid_fuse_lite<<<T_TOK, 64, 0, stream>>>(qkv_ab, positions, ropet, kfull);

    // 3+4 merged: q = (qkv_a @ g.w_q_b)*rq || kv = (qkv_a @ g.w_kv_b)*rkv
    gemm_dual<<<896, 256, 0, stream>>>(qkv_ab, wt_q_b, qbuf, wt_kv_b, kfull, vT,
                                       sq_q, sq_kv);

    // 5. flash attention (48 KB LDS, 3 blocks/CU) + combine
    attn_part<<<1024, 256, 0, stream>>>(qbuf, kfull, vT, ropet, oP0, oP1, l_part);
    attn_combine<<<(T_TOK * 256) / 256, 256, 0, stream>>>(oP0, oP1, l_part, attn_o);

    // 6. out = attn_o @ w_o
    gemm_out<<<dim3(HID / 128, T_TOK / 128), 256, 0, stream>>>(attn_o, wt_o, out);
}

// Round 13
// 301.238 us; speedup vs baseline: 1.2994x; 1.2994x over previous
//
#include <hip/hip_runtime.h>
#include <hip/hip_bf16.h>
#include <math.h>

typedef __bf16 bf16_t;
typedef __bf16 bf16x8 __attribute__((ext_vector_type(8)));
typedef float floatx4 __attribute__((ext_vector_type(4)));
typedef int intx4 __attribute__((ext_vector_type(4)));

#define T_TOK 2048
#define HID 2048
#define NH 16
#define D_NOPE 128
#define D_ROPE 64
#define D_QK 192
#define D_V 128
#define Q_LORA 1536
#define KV_LORA 512
#define QKV_N 2112            // 1536+512+64
#define QKV_NPAD 2176         // padded to 17*128
#define SCALING 0.07216878364870323f
#define LOG2E 1.442695041f
#define EXP_C1 (SCALING * LOG2E)      // score -> exp2 arg scale
#define EXP_C2 (12.0f * LOG2E)        // fixed bias (replaces online max; safe to s~100)

#define MFMA_BF16(a, b, c) __builtin_amdgcn_mfma_f32_16x16x32_bf16(a, b, c, 0, 0, 0)

// async 16B global->LDS (verified m97 pattern; LDS dest must be lane-linear)
__device__ __forceinline__ void gload16(const void* g, void* l) {
    __builtin_amdgcn_global_load_lds(
        (const __attribute__((address_space(1))) unsigned int*)g,
        (__attribute__((address_space(3))) unsigned int*)l, 16, 0, 0);
}

// ---------------------------------------------------------------------------
// MFMA GEMM body (round-8 verified: 256 threads, 128x128 tile, BK=64,
// 2-phase dbuf + chunk-XOR swizzle). Ast/Bst = row strides (may differ from K
// so A can be a column-slice of a wider matrix).
// MODE 0: fp32 C (gemm_o).
// MODE 1: bf16 C scaled by rq[row] from sqq   (q_b GEMM; rmsnorm fused).
// MODE 2: kv epilogue scaled by rkv[row]: k-nope -> kfull (192-stride),
//         v -> transposed write to vT[h][d][t] via LDS.
// MODE 3: bf16 C + per-row sumsq atomics (qkv_a GEMM; feeds rmsnorm).
// ---------------------------------------------------------------------------
template <int MODE>
__device__ __forceinline__ void gemm_body(
    const bf16_t* __restrict__ A, const bf16_t* __restrict__ Bt,
    float* __restrict__ Cf, bf16_t* __restrict__ Cb,
    bf16_t* __restrict__ kfull, bf16_t* __restrict__ vT,
    float* __restrict__ sqq, float* __restrict__ sqkv,
    int N, int K, int Ast, int Bst, int m0, int n0, bf16_t* S)
{
    bf16_t* As = S;               // 2 x 8192
    bf16_t* Bs = S + 16384;       // 2 x 8192
    const int tid = threadIdx.x;
    const int lane = tid & 63;
    const int w = tid >> 6;
    const int wm = w >> 1, wn = w & 1;
    const int l15 = lane & 15, quad = lane >> 4;
    const int ckey = (l15 >> 1) & 3;           // read-side chunk XOR key

    floatx4 acc[4][4] = {};

// stage tile (k0_) into buffer db_; source chunk pre-swizzled so that
// LDS[kk2][r][c] holds global chunk c ^ ((r>>1)&3)  (involution)
#define GSTAGE(db_, k0_)                                                                 \
    do {                                                                                 \
        _Pragma("unroll")                                                                \
        for (int it = 0; it < 4; ++it) {                                                 \
            int slot = it * 256 + tid;                                                   \
            int kk2 = slot >> 9;                                                         \
            int r = (slot >> 2) & 127;                                                   \
            int c = slot & 3;                                                            \
            int cs = c ^ ((r >> 1) & 3);                                                 \
            gload16((const char*)(A + (size_t)(m0 + r) * Ast + (k0_) + kk2 * 32 + cs * 8),\
                    (char*)(As + (size_t)(db_)*8192) + slot * 16);                       \
            gload16((const char*)(Bt + (size_t)(n0 + r) * Bst + (k0_) + kk2 * 32 + cs * 8),\
                    (char*)(Bs + (size_t)(db_)*8192) + slot * 16);                       \
        }                                                                                \
    } while (0)

    GSTAGE(0, 0);
    int db = 0;
    for (int k0 = 0; k0 < K; k0 += 64) {
        __syncthreads();                       // drains prefetch (issued 1 phase ago)
        if (k0 + 64 < K) GSTAGE(db ^ 1, k0 + 64);
        const bf16_t* Ab = As + (size_t)db * 8192;
        const bf16_t* Bb = Bs + (size_t)db * 8192;
#pragma unroll
        for (int kk2 = 0; kk2 < 2; ++kk2) {
            bf16x8 af[4], bfr[4];
#pragma unroll
            for (int mi = 0; mi < 4; ++mi)
                af[mi] = *(const bf16x8*)(Ab + kk2 * 4096 +
                                          (wm * 64 + mi * 16 + l15) * 32 +
                                          (quad ^ ckey) * 8);
#pragma unroll
            for (int ni = 0; ni < 4; ++ni)
                bfr[ni] = *(const bf16x8*)(Bb + kk2 * 4096 +
                                           (wn * 64 + ni * 16 + l15) * 32 +
                                           (quad ^ ckey) * 8);
#pragma unroll
            for (int mi = 0; mi < 4; ++mi)
#pragma unroll
                for (int ni = 0; ni < 4; ++ni)
                    acc[mi][ni] = MFMA_BF16(af[mi], bfr[ni], acc[mi][ni]);
        }
        db ^= 1;
    }
#undef GSTAGE

    if (MODE == 3) {
        // bf16 C + per-row sumsq (bucket by n0: q cols <1536, kv [1536,2048))
#pragma unroll
        for (int mi = 0; mi < 4; ++mi)
#pragma unroll
            for (int ni = 0; ni < 4; ++ni)
#pragma unroll
                for (int r = 0; r < 4; ++r) {
                    int row = m0 + wm * 64 + mi * 16 + quad * 4 + r;
                    int col = n0 + wn * 64 + ni * 16 + l15;
                    Cb[(size_t)row * N + col] = (bf16_t)acc[mi][ni][r];
                }
        float* sq = (n0 + 128 <= Q_LORA) ? sqq
                  : ((n0 >= Q_LORA && n0 + 128 <= Q_LORA + KV_LORA) ? sqkv : nullptr);
        if (sq) {
#pragma unroll
            for (int mi = 0; mi < 4; ++mi)
#pragma unroll
                for (int r = 0; r < 4; ++r) {
                    float s = 0.f;
#pragma unroll
                    for (int ni = 0; ni < 4; ++ni) {
                        float v = acc[mi][ni][r]; s += v * v;
                    }
                    s += __shfl_xor(s, 1); s += __shfl_xor(s, 2);
                    s += __shfl_xor(s, 4); s += __shfl_xor(s, 8);
                    if (l15 == 0)
                        atomicAdd(&sq[m0 + wm * 64 + mi * 16 + quad * 4 + r], s);
                }
        }
        return;
    }

    if (MODE == 1) {
        // q = (qkv_a @ g.w_q_b) * rq[row]   (rmsnorm scale commuted to output)
#pragma unroll
        for (int mi = 0; mi < 4; ++mi)
#pragma unroll
            for (int r = 0; r < 4; ++r) {
                int row = m0 + wm * 64 + mi * 16 + quad * 4 + r;
                float rq = rsqrtf(sqq[row] * (1.f / Q_LORA) + 1e-6f);
#pragma unroll
                for (int ni = 0; ni < 4; ++ni) {
                    int col = n0 + wn * 64 + ni * 16 + l15;
                    Cb[(size_t)row * N + col] = (bf16_t)(acc[mi][ni][r] * rq);
                }
            }
        return;
    }

    if (MODE == 2) {
        const int hh = n0 >> 8;
        if ((n0 & 255) == 0) {
            // ---- k-nope block ----
#pragma unroll
            for (int mi = 0; mi < 4; ++mi)
#pragma unroll
                for (int r = 0; r < 4; ++r) {
                    int row = m0 + wm * 64 + mi * 16 + quad * 4 + r;
                    float rkv = rsqrtf(sqkv[row] * (1.f / KV_LORA) + 1e-6f);
#pragma unroll
                    for (int ni = 0; ni < 4; ++ni) {
                        int dd = wn * 64 + ni * 16 + l15;
                        kfull[((size_t)hh * T_TOK + row) * 192 + dd] =
                            (bf16_t)(acc[mi][ni][r] * rkv);
                    }
                }
        } else {
            // ---- v block: scale + transpose via LDS, write vT[h][d][t] ----
            __syncthreads();                   // all waves done reading As/Bs
            bf16_t* Tq = S;                    // [128 d][stride 136] bf16
#pragma unroll
            for (int mi = 0; mi < 4; ++mi)
#pragma unroll
                for (int r = 0; r < 4; ++r) {
                    int rloc = wm * 64 + mi * 16 + quad * 4 + r;    // t - m0
                    float rkv = rsqrtf(sqkv[m0 + rloc] * (1.f / KV_LORA) + 1e-6f);
#pragma unroll
                    for (int ni = 0; ni < 4; ++ni) {
                        int cloc = wn * 64 + ni * 16 + l15;         // d
                        Tq[cloc * 136 + rloc] = (bf16_t)(acc[mi][ni][r] * rkv);
                    }
                }
            __syncthreads();
#pragma unroll
            for (int pass = 0; pass < 8; ++pass) {
                int dcol = pass * 16 + w * 4 + quad;
                bf16x8 vv = *(const bf16x8*)(Tq + dcol * 136 + l15 * 8);
                *(bf16x8*)(vT + ((size_t)hh * 128 + dcol) * T_TOK + m0 + l15 * 8) = vv;
            }
        }
        return;
    }

    // MODE 0: fp32 C
#pragma unroll
    for (int mi = 0; mi < 4; ++mi)
#pragma unroll
        for (int ni = 0; ni < 4; ++ni)
#pragma unroll
            for (int r = 0; r < 4; ++r) {
                int row = m0 + wm * 64 + mi * 16 + quad * 4 + r;
                int col = n0 + wn * 64 + ni * 16 + l15;
                Cf[(size_t)row * N + col] = acc[mi][ni][r];
            }
}

// qkv_a GEMM: bf16 out + sumsq atomics (rmsnorm stats fused into epilogue)
__global__ __launch_bounds__(256) void gemm_qkv_a(
    const bf16_t* __restrict__ hbf, const bf16_t* __restrict__ wt,
    bf16_t* __restrict__ qkv_ab, float* __restrict__ sqq, float* __restrict__ sqkv)
{
    __shared__ __align__(16) bf16_t S[4 * 8192];    // 64 KB
    gemm_body<3>(hbf, wt, nullptr, qkv_ab, nullptr, nullptr, sqq, sqkv,
                 QKV_NPAD, HID, HID, HID, blockIdx.y * 128, blockIdx.x * 128, S);
}

// Merged q_b + kv_b GEMMs, both reading raw bf16 qkv_a (stride 2176) with
// the rmsnorm row-scale applied in the epilogue (qn/kvn eliminated).
__global__ __launch_bounds__(256) void gemm_dual(
    const bf16_t* __restrict__ qkv_ab, const bf16_t* __restrict__ wqb,
    bf16_t* __restrict__ qbuf, const bf16_t* __restrict__ wkvb,
    bf16_t* __restrict__ kfull, bf16_t* __restrict__ vT,
    float* __restrict__ sqq, float* __restrict__ sqkv)
{
    __shared__ __align__(16) bf16_t S[4 * 8192];    // 64 KB
    int id = blockIdx.x;
    if (id < 384) {
        gemm_body<1>(qkv_ab, wqb, nullptr, qbuf, nullptr, nullptr, sqq, nullptr,
                     3072, Q_LORA, QKV_NPAD, Q_LORA,
                     (id / 24) * 128, (id % 24) * 128, S);
    } else {
        int i2 = id - 384;
        gemm_body<2>(qkv_ab + Q_LORA, wkvb, nullptr, nullptr, kfull, vT,
                     nullptr, sqkv,
                     4096, KV_LORA, QKV_NPAD, KV_LORA,
                     (i2 / 32) * 128, (i2 % 32) * 128, S);
    }
}

__global__ __launch_bounds__(256) void gemm_out(
    const bf16_t* __restrict__ attn_o, const bf16_t* __restrict__ wto,
    float* __restrict__ out)
{
    __shared__ __align__(16) bf16_t S[4 * 8192];    // 64 KB
    gemm_body<0>(attn_o, wto, out, nullptr, nullptr, nullptr, nullptr, nullptr,
                 HID, HID, HID, HID, blockIdx.y * 128, blockIdx.x * 128, S);
}

// ---------------------------------------------------------------------------
// Weight prep: 4 weight transposes (g_q/g_kv folded into w_q_b/w_kv_b) +
// hidden fp32->bf16 cvt + sumsq-buffer zeroing, one launch.
// ---------------------------------------------------------------------------
__global__ void transpose_all(const float* __restrict__ w0, const float* __restrict__ w1,
                              const float* __restrict__ w2, const float* __restrict__ w3,
                              const float* __restrict__ hidden,
                              const float* __restrict__ g_q, const float* __restrict__ g_kv,
                              bf16_t* __restrict__ o0, bf16_t* __restrict__ o1,
                              bf16_t* __restrict__ o2, bf16_t* __restrict__ o3,
                              bf16_t* __restrict__ hbf, float* __restrict__ sqbuf) {
    int n0 = blockIdx.x * 32, k0 = blockIdx.y * 32;
    int tx = threadIdx.x, ty = threadIdx.y;
    if (blockIdx.z == 4) {      // cvt hidden -> hbf + zero sq buffers
        if (blockIdx.x == 0 && blockIdx.y == 0) {
            int t = ty * 32 + tx;
            for (int j = t; j < 4096; j += 256) sqbuf[j] = 0.f;
        }
        if (n0 >= 2048 || k0 >= 2048) return;
        for (int i = ty; i < 32; i += 8)
            hbf[(size_t)(k0 + i) * 2048 + n0 + tx] =
                (bf16_t)hidden[(size_t)(k0 + i) * 2048 + n0 + tx];
        return;
    }
    const float* in; bf16_t* out; const float* g; int K, N;
    switch (blockIdx.z) {
        case 0: in = w0; out = o0; g = nullptr; K = 2048; N = 2112; break;
        case 1: in = w1; out = o1; g = g_q;     K = 1536; N = 3072; break;
        case 2: in = w2; out = o2; g = g_kv;    K = 512;  N = 4096; break;
        default: in = w3; out = o3; g = nullptr; K = 2048; N = 2048; break;
    }
    if (n0 >= N || k0 >= K) return;
    __shared__ float tile[32][33];
    for (int i = ty; i < 32; i += 8)
        tile[i][tx] = in[(size_t)(k0 + i) * N + n0 + tx];
    __syncthreads();
    float gk = g ? g[k0 + tx] : 1.f;
    for (int i = ty; i < 32; i += 8)
        out[(size_t)(n0 + i) * K + k0 + tx] = (bf16_t)(tile[tx][i] * gk);
}

// ---------------------------------------------------------------------------
// mid_fuse_lite: Q-rope cos/sin table + rope(k_pe) broadcast into
// kfull[h][t][128..192). (rmsnorm stats + qn/kvn now fused into the GEMMs.)
// ---------------------------------------------------------------------------
__global__ void mid_fuse_lite(const bf16_t* __restrict__ qkv_ab,
                              const int* __restrict__ pos,
                              float2* __restrict__ ropet, bf16_t* __restrict__ kfull) {
    int t = blockIdx.x, tid = threadIdx.x;
    if (tid >= 32) return;
    int i = tid;
    double inv = pow(10000.0, -(double)(2 * i) / 64.0);
    double fd = (double)pos[t] * inv;
    float c = (float)cos(fd), s = (float)sin(fd);
    ropet[t * 32 + i] = make_float2(c, s);
    float x1 = (float)qkv_ab[(size_t)t * QKV_NPAD + Q_LORA + KV_LORA + 2 * i];
    float x2 = (float)qkv_ab[(size_t)t * QKV_NPAD + Q_LORA + KV_LORA + 2 * i + 1];
    bf16_t v0 = (bf16_t)(x1 * c - x2 * s);
    bf16_t v1 = (bf16_t)(x1 * s + x2 * c);
#pragma unroll
    for (int h = 0; h < NH; ++h) {
        kfull[((size_t)h * T_TOK + t) * 192 + 128 + 2 * i] = v0;
        kfull[((size_t)h * T_TOK + t) * 192 + 128 + 2 * i + 1] = v1;
    }
}

// ---------------------------------------------------------------------------
// Flash attention v9b — 48 KB LDS diet schedule (round-12 structure, which
// passed numerically) with the REGISTER-CAP FIX: __launch_bounds__(256, 2).
// Round 12's (256,3) capped the allocator below the ~128-VGPR live set ->
// accumulator spills (VGPR 84, 508 MB scratch I/O, MfmaUtil 0.1%). With
// (256,2) the twin body allocated 128 VGPR spill-free (round 11); at 128
// VGPR the HW allows 16 waves/CU and the 48 KB LDS then gives 3 blocks/CU.
// ---------------------------------------------------------------------------
__global__ __launch_bounds__(256, 2) void attn_part(
    const bf16_t* __restrict__ qbuf, const bf16_t* __restrict__ kfull,
    const bf16_t* __restrict__ vT, const float2* __restrict__ ropet,
    bf16_t* __restrict__ oP0, bf16_t* __restrict__ oP1, float* __restrict__ l_part)
{
    const int id = blockIdx.x;
    const int h = id & 15;
    const int c = (id >> 4) & 3;
    const int qt = 15 - (id >> 6);
    const int q0 = qt * 128;
    const int nTile = 2 * (qt + 1);
    const int tbase = nTile >> 2, trem = nTile & 3;    // trem in {0,2}
    const int sz = tbase + (c < trem ? 1 : 0);
    const int sBeg = c * tbase + (c < trem ? c : trem);
    const int sEnd = sBeg + sz;
    const int unit = qt * 16 + h;
    const int tid = threadIdx.x, lane = tid & 63, w = tid >> 6;
    const int l15 = lane & 15, quad = lane >> 4;
    const int ckey = (l15 >> 1) & 3;                   // read-side chunk XOR key

    __shared__ __align__(16) bf16_t kn[6 * 64 * 32];       // 24 KB single (K incl. pe)
    __shared__ __align__(16) bf16_t vt2[2 * 128 * 32];     // 16 KB
    __shared__ __align__(16) bf16_t p_s[128 * 32];         // 8 KB half-P, swizzled

    // Q fragments: 2 strips x 6 k-steps (rows q0 + w*32 + st*16 + l15)
    bf16x8 qf[2][6];
#pragma unroll
    for (int st = 0; st < 2; ++st) {
        const bf16_t* qp = qbuf + (size_t)(q0 + w * 32 + st * 16 + l15) * (NH * D_QK) +
                           h * D_QK;
#pragma unroll
        for (int kk = 0; kk < 6; ++kk)
            qf[st][kk] = *(const bf16x8*)(qp + kk * 32 + quad * 8);
    }
    // in-register rope on q_pe (cols 128..191 -> kk 4,5)
#pragma unroll
    for (int st = 0; st < 2; ++st) {
        int t = q0 + w * 32 + st * 16 + l15;
#pragma unroll
        for (int kk = 4; kk < 6; ++kk)
#pragma unroll
            for (int p = 0; p < 4; ++p) {
                float2 cs = ropet[t * 32 + (kk - 4) * 16 + quad * 4 + p];
                float x1 = (float)qf[st][kk][2 * p], x2 = (float)qf[st][kk][2 * p + 1];
                qf[st][kk][2 * p] = (bf16_t)(x1 * cs.x - x2 * cs.y);
                qf[st][kk][2 * p + 1] = (bf16_t)(x1 * cs.y + x2 * cs.x);
            }
    }

    bf16x8 ones;
#pragma unroll
    for (int j = 0; j < 8; ++j) ones[j] = (bf16_t)1.0f;

    floatx4 o[2][8] = {};
    floatx4 lac[2] = {};
    intx4 vreg[4];

// K staging: gload_lds dest is lane-linear, so pre-swizzle the GLOBAL source
// chunk (cc ^ (s>>1)&3); reads undo it with quad ^ ckey (involution).
#define STAGE_KN(s0_)                                                                    \
    do {                                                                                 \
        _Pragma("unroll")                                                                \
        for (int it = 0; it < 6; ++it) {                                                 \
            int slot = it * 256 + tid;                                                   \
            int kk = slot >> 8, s = (slot >> 2) & 63, cc = slot & 3;                     \
            int cs = cc ^ ((s >> 1) & 3);                                                \
            gload16((const char*)(kfull + ((size_t)h * T_TOK + (s0_) + s) * 192 +        \
                                  kk * 32 + cs * 8),                                     \
                    (char*)kn + slot * 16);                                              \
        }                                                                                \
    } while (0)

// V staging split (T14): issue loads early (latency hides under compute),
// ds_write late at the SWIZZLED LDS position.
#define VLOAD(s0_)                                                                       \
    do {                                                                                 \
        _Pragma("unroll")                                                                \
        for (int it = 0; it < 4; ++it) {                                                 \
            int slot = it * 256 + tid;                                                   \
            int ks = slot >> 9, d = (slot >> 2) & 127, cc = slot & 3;                    \
            vreg[it] = *(const intx4*)(vT + ((size_t)h * 128 + d) * T_TOK + (s0_) +      \
                                       ks * 32 + cc * 8);                                \
        }                                                                                \
    } while (0)

#define VWRITE()                                                                         \
    do {                                                                                 \
        _Pragma("unroll")                                                                \
        for (int it = 0; it < 4; ++it) {                                                 \
            int slot = it * 256 + tid;                                                   \
            int ks = slot >> 9, d = (slot >> 2) & 127, cc = slot & 3;                    \
            *(intx4*)((char*)vt2 +                                                       \
                      (size_t)((ks * 512 + d * 4 + (cc ^ ((d >> 1) & 3))) * 16)) =       \
                vreg[it];                                                                \
        }                                                                                \
    } while (0)

    if (sz > 0) {
        STAGE_KN(sBeg * 64);
        VLOAD(sBeg * 64);
        VWRITE();
    }

    for (int si = sBeg; si < sEnd; ++si) {
        const int s0 = si * 64;
        __syncthreads();                        // (A) kn + vt ready (prev writes done)

        // ---- S = Q K^T (B-frags shared across strips) ----
        floatx4 s_acc[2][4] = {};
        __builtin_amdgcn_s_setprio(1);
#pragma unroll
        for (int ni = 0; ni < 4; ++ni) {
#pragma unroll
            for (int kk = 0; kk < 6; ++kk) {
                bf16x8 b = *(const bf16x8*)(kn + kk * 2048 +
                                            (ni * 16 + l15) * 32 + (quad ^ ckey) * 8);
                s_acc[0][ni] = MFMA_BF16(qf[0][kk], b, s_acc[0][ni]);
                s_acc[1][ni] = MFMA_BF16(qf[1][kk], b, s_acc[1][ni]);
            }
        }
        __builtin_amdgcn_s_setprio(0);

        __syncthreads();                        // (B) all waves done reading kn
        if (si + 1 < sEnd) {
            STAGE_KN(s0 + 64);                  // async into kn; lands under softmax+PV
            VLOAD(s0 + 64);                     // V regs: same window
        }

        // ---- per ks-half: softmax (ni=2ks,2ks+1) -> p_s, then PV(ks) ----
        const bool diag = (si >= 2 * qt);
#pragma unroll
        for (int ks = 0; ks < 2; ++ks) {
#pragma unroll
            for (int st = 0; st < 2; ++st)
#pragma unroll
                for (int nl = 0; nl < 2; ++nl)
#pragma unroll
                    for (int r = 0; r < 4; ++r) {
                        int prow = w * 32 + st * 16 + quad * 4 + r;
                        int cloc = nl * 16 + l15;
                        float pv = exp2f(s_acc[st][ks * 2 + nl][r] * EXP_C1 - EXP_C2);
                        if (diag && (s0 + ks * 32 + cloc) > (q0 + prow)) pv = 0.f;
                        p_s[prow * 32 + ((((cloc >> 3) ^ ((prow >> 1) & 3))) << 3) +
                            (cloc & 7)] = (bf16_t)pv;
                    }
            __builtin_amdgcn_s_setprio(1);
            bf16x8 a0, a1;
            {
                int arow = w * 32 + l15;
                a0 = *(const bf16x8*)(p_s + arow * 32 +
                                      ((quad ^ ((arow >> 1) & 3)) << 3));
                arow += 16;
                a1 = *(const bf16x8*)(p_s + arow * 32 +
                                      ((quad ^ ((arow >> 1) & 3)) << 3));
            }
            lac[0] = MFMA_BF16(a0, ones, lac[0]);
            lac[1] = MFMA_BF16(a1, ones, lac[1]);
#pragma unroll
            for (int ni = 0; ni < 8; ++ni) {
                bf16x8 b = *(const bf16x8*)(vt2 + ks * 4096 +
                                            (ni * 16 + l15) * 32 + (quad ^ ckey) * 8);
                o[0][ni] = MFMA_BF16(a0, b, o[0][ni]);
                o[1][ni] = MFMA_BF16(a1, b, o[1][ni]);
            }
            __builtin_amdgcn_s_setprio(0);
        }

        __syncthreads();                        // (C) vt free + prefetch vmcnt drained
        if (si + 1 < sEnd) VWRITE();            // write next V (regs landed)
    }

    // ---- write partials: o (bf16, unnormalized) + l (fp32) ----
    bf16_t* op = ((c < 2) ? oP0 : oP1) + (size_t)(unit * 2 + (c & 1)) * 128 * 128;
#pragma unroll
    for (int st = 0; st < 2; ++st) {
#pragma unroll
        for (int ni = 0; ni < 8; ++ni)
#pragma unroll
            for (int r = 0; r < 4; ++r) {
                int lrow = w * 32 + st * 16 + quad * 4 + r;
                op[(size_t)lrow * 128 + ni * 16 + l15] = (bf16_t)o[st][ni][r];
            }
        if (l15 == 0)
#pragma unroll
            for (int r = 0; r < 4; ++r) {
                int lrow = w * 32 + st * 16 + quad * 4 + r;
                l_part[((size_t)unit * 4 + c) * 128 + lrow] = lac[st][r];
            }
    }
#undef STAGE_KN
#undef VLOAD
#undef VWRITE
}

// ---------------------------------------------------------------------------
// Combine: attn_o = (o0+o1+o2+o3) / (l0+l1+l2+l3)
// ---------------------------------------------------------------------------
__global__ void attn_combine(const bf16_t* __restrict__ oP0,
                             const bf16_t* __restrict__ oP1,
                             const float* __restrict__ l_part,
                             bf16_t* __restrict__ attn_o)
{
    int idx = blockIdx.x * 256 + threadIdx.x;   // t*256 + col-group (8 cols each)
    int t = idx >> 8, cg = idx & 255;
    int col = cg * 8;
    int h = col >> 7, d = col & 127;
    int qt = t >> 7, lrow = t & 127;
    size_t unit = (size_t)qt * 16 + h;
    const float* lp = l_part + unit * 4 * 128 + lrow;
    float inv = 1.f / (lp[0] + lp[128] + lp[256] + lp[384]);
    size_t r0 = ((unit * 2 + 0) * 128 + lrow) * 128 + d;
    size_t r1 = ((unit * 2 + 1) * 128 + lrow) * 128 + d;
    bf16x8 a0 = *(const bf16x8*)(oP0 + r0);
    bf16x8 a1 = *(const bf16x8*)(oP0 + r1);
    bf16x8 a2 = *(const bf16x8*)(oP1 + r0);
    bf16x8 a3 = *(const bf16x8*)(oP1 + r1);
    bf16x8 out;
#pragma unroll
    for (int j = 0; j < 8; ++j)
        out[j] = (bf16_t)(((float)a0[j] + (float)a1[j] + (float)a2[j] + (float)a3[j]) * inv);
    *(bf16x8*)(attn_o + (size_t)t * (NH * D_V) + col) = out;
}

// ---------------------------------------------------------------------------
extern "C" void kernel_launch(void* const* d_in, const int* in_sizes, int n_in,
                              void* d_out, int out_size, void* d_ws, size_t ws_size,
                              hipStream_t stream) {
    const float* hidden = (const float*)d_in[0];
    const int* positions = (const int*)d_in[1];
    const float* w_qkv_a = (const float*)d_in[2];
    const float* g_q = (const float*)d_in[3];
    const float* w_q_b = (const float*)d_in[4];
    const float* g_kv = (const float*)d_in[5];
    const float* w_kv_b = (const float*)d_in[6];
    const float* w_o = (const float*)d_in[7];
    float* out = (float*)d_out;

    // ---- workspace layout (~94.5 MB, round-8 region map) ----
    char* p = (char*)d_ws;
    bf16_t* qkv_ab = (bf16_t*)p;                    // [2048][2176] bf16 (8.9 MB)
    bf16_t* attn_o = (bf16_t*)p;                    // alias (qkv_ab dead by then)
    p += (size_t)T_TOK * QKV_NPAD * 4;              // region still fp32-sized
    bf16_t* hbf = (bf16_t*)p;                       // [2048][2048] bf16
    p += (size_t)T_TOK * HID * 2;
    bf16_t* qbuf = (bf16_t*)p;  p += (size_t)T_TOK * NH * D_QK * 2;   // [2048][3072]
    bf16_t* vtmp = (bf16_t*)p;  p += (size_t)T_TOK * NH * D_V * 2;    // scratch region
    bf16_t* kfull = (bf16_t*)p; p += (size_t)NH * T_TOK * 192 * 2;    // [16][2048][192]
    bf16_t* vT = (bf16_t*)p;    p += (size_t)NH * 128 * T_TOK * 2;    // [16][128][2048]
    bf16_t* wt_qkv_a = (bf16_t*)p; p += (size_t)QKV_NPAD * HID * 2;   // [2176][2048]
    bf16_t* wt_q_b = (bf16_t*)p;   p += (size_t)3072 * Q_LORA * 2;    // [3072][1536]
    bf16_t* wt_kv_b = (bf16_t*)p;  p += (size_t)4096 * KV_LORA * 2;   // [4096][512]
    bf16_t* wt_o = (bf16_t*)p;                                        // [2048][2048]

    // overlays of dead-by-then regions:
    //   ropet  f32x2 [2048][32] = 512 KB at vtmp+0      (written mid_fuse_lite)
    //   l_part f32 [256][4][128] = 512 KB at vtmp+1MB
    //   sq_q/sq_kv f32 2048+2048 = 16 KB at vtmp+2MB    (zeroed transpose_all)
    //   oP0 bf16 [256][2][128][128] = 16.78 MB over wt_qkv_a + wt_q_b
    //   oP1 bf16 [256][2][128][128] = 16.78 MB over qkv_ab tail + hbf
    float2* ropet = (float2*)vtmp;
    float* l_part = (float*)((char*)vtmp + (1 << 20));
    float* sq_q = (float*)((char*)vtmp + (2 << 20));
    float* sq_kv = sq_q + 2048;
    bf16_t* oP0 = wt_qkv_a;
    bf16_t* oP1 = (bf16_t*)((char*)d_ws + (size_t)T_TOK * HID * 2);

    dim3 tb(32, 8);

    // 0. weight transposes (g folded into w_q_b/w_kv_b) + hidden cvt + sq zero
    transpose_all<<<dim3(128, 64, 5), tb, 0, stream>>>(
        w_qkv_a, w_q_b, w_kv_b, w_o, hidden, g_q, g_kv,
        wt_qkv_a, wt_q_b, wt_kv_b, wt_o, hbf, sq_q);

    // 1. qkv_a (bf16) = hidden @ w_qkv_a, + per-row sumsq atomics
    gemm_qkv_a<<<dim3(QKV_NPAD / 128, T_TOK / 128), 256, 0, stream>>>(
        hbf, wt_qkv_a, qkv_ab, sq_q, sq_kv);

    // 2. rope table + rope(k_pe)->kfull (rmsnorm now lives in the GEMMs)
    mid_fuse_lite<<<T_TOK, 64, 0, stream>>>(qkv_ab, positions, ropet, kfull);

    // 3+4 merged: q = (qkv_a @ g.w_q_b)*rq || kv = (qkv_a @ g.w_kv_b)*rkv
    gemm_dual<<<896, 256, 0, stream>>>(qkv_ab, wt_q_b, qbuf, wt_kv_b, kfull, vT,
                                       sq_q, sq_kv);

    // 5. flash attention (48 KB LDS, 3 blocks/CU via natural 128-VGPR fit)
    attn_part<<<1024, 256, 0, stream>>>(qbuf, kfull, vT, ropet, oP0, oP1, l_part);
    attn_combine<<<(T_TOK * 256) / 256, 256, 0, stream>>>(oP0, oP1, l_part, attn_o);

    // 6. out = attn_o @ w_o
    gemm_out<<<dim3(HID / 128, T_TOK / 128), 256, 0, stream>>>(attn_o, wt_o, out);
}